// Round 3
// baseline (960.146 us; speedup 1.0000x reference)
//
#include <hip/hip_runtime.h>
#include <hip/hip_bf16.h>

typedef unsigned short u16;
typedef short bf16x8 __attribute__((ext_vector_type(8)));
typedef float f32x4 __attribute__((ext_vector_type(4)));

#define N_ 32
#define G_ 197
#define C_ 768
#define HEADS_ 12
#define D_ 64
#define HH_ 14
#define FF_ 8
#define MLP_ 3072
#define MPAD 6400
#define MROWS 6304

__device__ __forceinline__ u16 f2bf(float f) {
    unsigned int u = __float_as_uint(f);
    u += 0x7FFF + ((u >> 16) & 1);
    return (u16)(u >> 16);
}

// ---------------- mixer reduce: msum[h,f,d] = sum_s mixer[h,f,d,s,:] ----------------
__global__ __launch_bounds__(256) void reduce_mixer(const float* __restrict__ mixer,
                                                    float2* __restrict__ msum) {
    int lane = threadIdx.x & 63;
    size_t widx = (size_t)blockIdx.x * 4 + (threadIdx.x >> 6);  // 0..86015 = (h*8+f)*768+d
    const float* base = mixer + widx * 1536;
    float re = 0.f, im = 0.f;
#pragma unroll
    for (int it = 0; it < 6; it++) {
        float4 v = *(const float4*)(base + it * 256 + lane * 4);
        re += v.x + v.z;
        im += v.y + v.w;
    }
#pragma unroll
    for (int o = 32; o; o >>= 1) {
        re += __shfl_xor(re, o);
        im += __shfl_xor(im, o);
    }
    if (lane == 0) msum[widx] = make_float2(re, im);
}

// ---------------- build spatial conv kernel k[d][da*14+db] ----------------
__global__ __launch_bounds__(256) void build_k(const float2* __restrict__ msum,
                                               float* __restrict__ kbuf) {
    int d = blockIdx.x;
    int tid = threadIdx.x;
    __shared__ float mre[112], mim[112], ct[14], st[14];
    if (tid < 112) {
        float2 v = msum[(size_t)tid * 768 + d];
        mre[tid] = v.x;
        mim[tid] = v.y;
    }
    if (tid >= 112 && tid < 126) {
        int j = tid - 112;
        float ang = 6.28318530717958647692f * (float)j / 14.f;
        ct[j] = cosf(ang);
        st[j] = sinf(ang);
    }
    __syncthreads();
    if (tid < 196) {
        int da = tid / 14, db = tid % 14;
        float acc = 0.f;
        for (int u = 0; u < 14; u++) {
            int idx = (u * da) % 14;
#pragma unroll
            for (int v = 0; v < 8; v++) {
                float w = (v == 0 || v == 7) ? 1.f : 2.f;
                acc += w * (mre[u * 8 + v] * ct[idx] - mim[u * 8 + v] * st[idx]);
                idx += db;
                if (idx >= 14) idx -= 14;
            }
        }
        kbuf[(size_t)d * 196 + tid] = acc * (1.f / 196.f);
    }
}

// ---------------- per-channel 14x14 circular conv ----------------
__device__ __forceinline__ void conv_proc(int a, int p, int lane, const float* kl,
                                          const float (&tq)[14], float (&ac)[14]) {
    int ra = a - p;
    if (ra < 0) ra += 14;
    const float* kr = &kl[lane * 197 + ra * 14];
    float kq[14];
#pragma unroll
    for (int i = 0; i < 14; i++) kq[i] = kr[i];
#pragma unroll
    for (int b = 0; b < 14; b++)
#pragma unroll
        for (int q = 0; q < 14; q++) ac[b] += tq[q] * kq[(b - q + 14) % 14];
}

__global__ __launch_bounds__(256) void conv_kernel(const float* __restrict__ x,
                                                   const float* __restrict__ kbuf,
                                                   float* __restrict__ t2) {
    __shared__ float tl[196 * 32];  // [s'][dlane]
    __shared__ float kl[32 * 197];  // [dlane][rel] pitch 197
    int n = blockIdx.x / 24;
    int d0 = (blockIdx.x % 24) * 32;
    int tid = threadIdx.x;
    for (int i = tid; i < 196 * 32; i += 256) {
        int s = i >> 5, dl = i & 31;
        tl[i] = x[((size_t)n * 197 + 1 + s) * 768 + d0 + dl];
    }
    for (int i = tid; i < 32 * 196; i += 256) {
        int dl = i / 196, j = i - dl * 196;
        kl[dl * 197 + j] = kbuf[(size_t)(d0 + dl) * 196 + j];
    }
    __syncthreads();
    int lane = tid & 31, sg = tid >> 5;
    bool two = (sg < 6);
    int a0 = two ? sg * 2 : 12 + (sg - 6);
    float acc0[14], acc1[14];
#pragma unroll
    for (int i = 0; i < 14; i++) {
        acc0[i] = 0.f;
        acc1[i] = 0.f;
    }
    for (int p = 0; p < 14; p++) {
        float tq[14];
#pragma unroll
        for (int q = 0; q < 14; q++) tq[q] = tl[(p * 14 + q) * 32 + lane];
        conv_proc(a0, p, lane, kl, tq, acc0);
        if (two) conv_proc(a0 + 1, p, lane, kl, tq, acc1);
    }
    __syncthreads();
#pragma unroll
    for (int b = 0; b < 14; b++) tl[(a0 * 14 + b) * 32 + lane] = acc0[b];
    if (two) {
#pragma unroll
        for (int b = 0; b < 14; b++) tl[((a0 + 1) * 14 + b) * 32 + lane] = acc1[b];
    }
    __syncthreads();
    for (int i = tid; i < 196 * 32; i += 256) {
        int s = i >> 5, dl = i & 31;
        t2[((size_t)n * 196 + s) * 768 + d0 + dl] = tl[i];
    }
}

// ---------------- attention (1 query per head, algebraically folded) ----------------
__device__ __forceinline__ float blk_sum(float v, float* red) {
    int lane = threadIdx.x & 63, wid = threadIdx.x >> 6;
#pragma unroll
    for (int o = 32; o; o >>= 1) v += __shfl_xor(v, o);
    if (lane == 0) red[wid] = v;
    __syncthreads();
    float r = red[0] + red[1] + red[2] + red[3];
    __syncthreads();
    return r;
}
__device__ __forceinline__ float blk_max(float v, float* red) {
    int lane = threadIdx.x & 63, wid = threadIdx.x >> 6;
#pragma unroll
    for (int o = 32; o; o >>= 1) v = fmaxf(v, __shfl_xor(v, o));
    if (lane == 0) red[wid] = v;
    __syncthreads();
    float r = fmaxf(fmaxf(red[0], red[1]), fmaxf(red[2], red[3]));
    __syncthreads();
    return r;
}

__global__ __launch_bounds__(256) void attn_kernel(
    const float* __restrict__ x, const float* __restrict__ t2, const float* __restrict__ Qw,
    const float* __restrict__ Qb, const float* __restrict__ Kw, const float* __restrict__ Kb,
    const float* __restrict__ Vw, const float* __restrict__ Vb, float* __restrict__ newcls) {
    int n = blockIdx.x / 12, h = blockIdx.x % 12;
    int tid = threadIdx.x;
    __shared__ float cls_s[64], Qp[64], gv[64], Aw[197], fv[64];
    __shared__ float red[8];
    const float* xn = x + (size_t)n * 197 * 768;
    if (tid < 64) cls_s[tid] = xn[h * 64 + tid];
    __syncthreads();
    if (tid < 64) {
        float s = 0.f;
        const float* qw = Qw + (size_t)tid * 768 + h * 64;
#pragma unroll 8
        for (int d = 0; d < 64; d++) s += cls_s[d] * qw[d];
        Qp[tid] = s + Qb[h];
    }
    __syncthreads();
    float sQ = blk_sum(tid < 64 ? Qp[tid] : 0.f, red);
    if (tid < 64) {
        float s = 0.f;
        for (int xq = 0; xq < 64; xq++) s += Qp[xq] * Kw[(size_t)xq * 768 + h * 64 + tid];
        gv[tid] = s;
    }
    __syncthreads();
    float apre = -3.0e38f;
    if (tid < 197) {
        const float* fr =
            (tid == 0) ? (xn + h * 64) : (t2 + ((size_t)n * 196 + tid - 1) * 768 + h * 64);
        float s = 0.f;
#pragma unroll 8
        for (int d = 0; d < 64; d++) s += fr[d] * gv[d];
        apre = (s + Kb[tid * 12 + h] * sQ) * 0.125f;
    }
    float mx = blk_max(apre, red);
    float p = (tid < 197) ? __expf(apre - mx) : 0.f;
    float denom = blk_sum(p, red);
    float sAV = blk_sum(tid < 197 ? p * Vb[tid * 12 + h] : 0.f, red) / denom;
    if (tid < 197) Aw[tid] = p / denom;
    __syncthreads();
    if (tid < 64) {
        float s = 0.f;
        for (int k = 0; k < 197; k++) {
            const float* fr = (k == 0) ? xn : (t2 + ((size_t)n * 196 + k - 1) * 768);
            s += Aw[k] * fr[h * 64 + tid];
        }
        fv[tid] = s;
    }
    __syncthreads();
    if (tid < 64) {
        float s = 0.f;
        for (int d = 0; d < 64; d++) s += fv[d] * Vw[(size_t)tid * 768 + h * 64 + d];
        newcls[(size_t)n * 768 + h * 64 + tid] = s + sAV;
    }
}

// ---------------- residual + layernorm; writes xo (fp32) and Y (bf16) ----------------
__global__ __launch_bounds__(256) void ln_kernel(const float* __restrict__ x,
                                                 const float* __restrict__ t2,
                                                 const float* __restrict__ newcls,
                                                 const float* __restrict__ lnw,
                                                 const float* __restrict__ lnb,
                                                 float* __restrict__ xo, u16* __restrict__ Y) {
    int row = blockIdx.x;
    int n = row / 197, g = row % 197;
    int tid = threadIdx.x;
    __shared__ float red[8], red2[8];
    const float* xr = x + (size_t)row * 768;
    const float* add = (g == 0) ? (newcls + (size_t)n * 768) : (t2 + ((size_t)n * 196 + g - 1) * 768);
    float v[3];
    float s = 0.f, s2 = 0.f;
#pragma unroll
    for (int j = 0; j < 3; j++) {
        int c = tid + j * 256;
        float t = xr[c] + add[c];
        v[j] = t;
        s += t;
        s2 += t * t;
    }
    int lane = tid & 63, wid = tid >> 6;
#pragma unroll
    for (int o = 32; o; o >>= 1) {
        s += __shfl_xor(s, o);
        s2 += __shfl_xor(s2, o);
    }
    if (lane == 0) {
        red[wid] = s;
        red2[wid] = s2;
    }
    __syncthreads();
    s = red[0] + red[1] + red[2] + red[3];
    s2 = red2[0] + red2[1] + red2[2] + red2[3];
    float mu = s * (1.f / 768.f);
    float var = s2 * (1.f / 768.f) - mu * mu;
    float rstd = 1.f / sqrtf(var + 1e-6f);
#pragma unroll
    for (int j = 0; j < 3; j++) {
        int c = tid + j * 256;
        float t = v[j];
        xo[(size_t)row * 768 + c] = t;
        float y = (t - mu) * rstd * lnw[c] + lnb[c];
        Y[(size_t)row * 768 + c] = f2bf(y);
    }
}

// ---------------- fp32 -> bf16 transpose (for B matrices) ----------------
__global__ __launch_bounds__(256) void transpose_to_bf16(const float* __restrict__ in,
                                                         u16* __restrict__ out, int R, int C) {
    __shared__ float tile[32][33];
    int c0 = blockIdx.x * 32, r0 = blockIdx.y * 32;
    int tx = threadIdx.x & 31, ty = threadIdx.x >> 5;
    for (int j = ty; j < 32; j += 8) tile[j][tx] = in[(size_t)(r0 + j) * C + c0 + tx];
    __syncthreads();
    for (int j = ty; j < 32; j += 8) out[(size_t)(c0 + j) * R + r0 + tx] = f2bf(tile[tx][j]);
}

// ---------------- 128x128 bf16 MFMA GEMM, C = A(MxK) * Bt(NxK)^T ----------------
// EPI 0: Hbuf (bf16) = gelu(acc + bias), no row guard (padded rows are junk, discarded later).
// EPI 1: out (fp32) = acc + bias + resid, rows < MROWS only.  <-- d_out is FLOAT32
template <int EPI>
__global__ __launch_bounds__(256) void gemm128(const u16* __restrict__ A, const u16* __restrict__ Bt,
                                               int K, const float* __restrict__ bias,
                                               const float* __restrict__ resid,
                                               void* __restrict__ outv, int Nt) {
    __shared__ __align__(16) u16 As[128 * 32];
    __shared__ __align__(16) u16 Bs[128 * 32];
    int m0 = blockIdx.y * 128, n0 = blockIdx.x * 128;
    int tid = threadIdx.x;
    int lane = tid & 63, w = tid >> 6, wr = w >> 1, wc = w & 1;
    int lr = lane & 15, lkb = (lane >> 4) * 8;
    int arow = tid >> 2, acol = (tid & 3) * 8;

    f32x4 acc[4][4];
#pragma unroll
    for (int i = 0; i < 4; i++)
#pragma unroll
        for (int j = 0; j < 4; j++) {
            f32x4 z = {0.f, 0.f, 0.f, 0.f};
            acc[i][j] = z;
        }

    for (int k0 = 0; k0 < K; k0 += 32) {
        *(uint4*)&As[arow * 32 + acol] = *(const uint4*)&A[(size_t)(m0 + arow) * K + k0 + acol];
        *(uint4*)&As[(arow + 64) * 32 + acol] =
            *(const uint4*)&A[(size_t)(m0 + arow + 64) * K + k0 + acol];
        *(uint4*)&Bs[arow * 32 + acol] = *(const uint4*)&Bt[(size_t)(n0 + arow) * K + k0 + acol];
        *(uint4*)&Bs[(arow + 64) * 32 + acol] =
            *(const uint4*)&Bt[(size_t)(n0 + arow + 64) * K + k0 + acol];
        __syncthreads();
        bf16x8 af[4], bfr[4];
#pragma unroll
        for (int i = 0; i < 4; i++) {
            af[i] = *(const bf16x8*)&As[(wr * 64 + i * 16 + lr) * 32 + lkb];
            bfr[i] = *(const bf16x8*)&Bs[(wc * 64 + i * 16 + lr) * 32 + lkb];
        }
#pragma unroll
        for (int mi = 0; mi < 4; mi++)
#pragma unroll
            for (int ni = 0; ni < 4; ni++)
                acc[mi][ni] =
                    __builtin_amdgcn_mfma_f32_16x16x32_bf16(af[mi], bfr[ni], acc[mi][ni], 0, 0, 0);
        __syncthreads();
    }

    int rbase = (lane >> 4) * 4;
#pragma unroll
    for (int mi = 0; mi < 4; mi++)
#pragma unroll
        for (int ni = 0; ni < 4; ni++) {
            int colg = n0 + wc * 64 + ni * 16 + lr;
#pragma unroll
            for (int r = 0; r < 4; r++) {
                int rowg = m0 + wr * 64 + mi * 16 + rbase + r;
                float a = acc[mi][ni][r];
                if (EPI == 0) {
                    float h = a + bias[colg];
                    h = 0.5f * h * (1.f + erff(h * 0.70710678118654752f));
                    ((u16*)outv)[(size_t)rowg * Nt + colg] = f2bf(h);
                } else {
                    if (rowg < MROWS) {
                        float h = a + bias[colg] + resid[(size_t)rowg * 768 + colg];
                        ((float*)outv)[(size_t)rowg * Nt + colg] = h;
                    }
                }
            }
        }
}

extern "C" void kernel_launch(void* const* d_in, const int* in_sizes, int n_in, void* d_out,
                              int out_size, void* d_ws, size_t ws_size, hipStream_t stream) {
    const float* x = (const float*)d_in[0];
    const float* mixer = (const float*)d_in[1];
    const float* Qw = (const float*)d_in[2];
    const float* Qb = (const float*)d_in[3];
    const float* Kw = (const float*)d_in[4];
    const float* Kb = (const float*)d_in[5];
    const float* Vw = (const float*)d_in[6];
    const float* Vb = (const float*)d_in[7];
    const float* lnw = (const float*)d_in[8];
    const float* lnb = (const float*)d_in[9];
    const float* w1 = (const float*)d_in[10];
    const float* b1 = (const float*)d_in[11];
    const float* w2 = (const float*)d_in[12];
    const float* b2 = (const float*)d_in[13];
    char* ws = (char*)d_ws;

    size_t off = 0;
    auto alloc = [&](size_t bytes) {
        size_t o = off;
        off += (bytes + 255) & ~(size_t)255;
        return o;
    };
    float2* msum = (float2*)(ws + alloc((size_t)14 * 8 * 768 * 8));
    float* kbuf = (float*)(ws + alloc((size_t)768 * 196 * 4));
    float* t2 = (float*)(ws + alloc((size_t)32 * 196 * 768 * 4));
    float* newcls = (float*)(ws + alloc((size_t)32 * 768 * 4));
    float* xo = (float*)(ws + alloc((size_t)32 * 197 * 768 * 4));
    u16* Ybuf = (u16*)(ws + alloc((size_t)MPAD * 768 * 2));
    u16* Hbuf = (u16*)(ws + alloc((size_t)MPAD * 3072 * 2));
    u16* w1t = (u16*)(ws + alloc((size_t)3072 * 768 * 2));
    u16* w2t = (u16*)(ws + alloc((size_t)768 * 3072 * 2));
    if (off > ws_size) return;

    transpose_to_bf16<<<dim3(3072 / 32, 768 / 32), 256, 0, stream>>>(w1, w1t, 768, 3072);
    transpose_to_bf16<<<dim3(768 / 32, 3072 / 32), 256, 0, stream>>>(w2, w2t, 3072, 768);
    reduce_mixer<<<21504, 256, 0, stream>>>(mixer, msum);
    build_k<<<768, 256, 0, stream>>>(msum, kbuf);
    conv_kernel<<<768, 256, 0, stream>>>(x, kbuf, t2);
    attn_kernel<<<384, 256, 0, stream>>>(x, t2, Qw, Qb, Kw, Kb, Vw, Vb, newcls);
    ln_kernel<<<6304, 256, 0, stream>>>(x, t2, newcls, lnw, lnb, xo, Ybuf);
    gemm128<0><<<dim3(3072 / 128, 50), 256, 0, stream>>>(Ybuf, w1t, 768, b1, nullptr, Hbuf, 3072);
    gemm128<1><<<dim3(768 / 128, 50), 256, 0, stream>>>(Hbuf, w2t, 3072, b2, xo, d_out, 768);
}

// Round 4
// 939.285 us; speedup vs baseline: 1.0222x; 1.0222x over previous
//
#include <hip/hip_runtime.h>
#include <hip/hip_bf16.h>

typedef unsigned short u16;
typedef short bf16x8 __attribute__((ext_vector_type(8)));
typedef float f32x4 __attribute__((ext_vector_type(4)));

#define N_ 32
#define G_ 197
#define C_ 768
#define HEADS_ 12
#define D_ 64
#define HH_ 14
#define FF_ 8
#define MLP_ 3072
#define MPAD 6400
#define MROWS 6304

__device__ __forceinline__ u16 f2bf(float f) {
    unsigned int u = __float_as_uint(f);
    u += 0x7FFF + ((u >> 16) & 1);
    return (u16)(u >> 16);
}

// async global->LDS 16B: lane l's 16B from g(lane-varying) lands at l(wave-uniform) + l*16
__device__ __forceinline__ void gld16(const void* g, void* l) {
#if __has_builtin(__builtin_amdgcn_global_load_lds)
    auto gp = reinterpret_cast<const __attribute__((address_space(1))) unsigned int*>(
        reinterpret_cast<uintptr_t>(g));
    auto lp = reinterpret_cast<__attribute__((address_space(3))) unsigned int*>(
        reinterpret_cast<uintptr_t>(l));
    __builtin_amdgcn_global_load_lds(gp, lp, 16, 0, 0);
#else
    int lane = threadIdx.x & 63;
    *(uint4*)((char*)l + lane * 16) = *(const uint4*)((const char*)g);
#endif
}

// ---------------- mixer reduce: msum[h,f,d] = sum_s mixer[h,f,d,s,:] ----------------
__global__ __launch_bounds__(256) void reduce_mixer(const float* __restrict__ mixer,
                                                    float2* __restrict__ msum) {
    int lane = threadIdx.x & 63;
    size_t widx = (size_t)blockIdx.x * 4 + (threadIdx.x >> 6);  // 0..86015 = (h*8+f)*768+d
    const float* base = mixer + widx * 1536;
    float re = 0.f, im = 0.f;
#pragma unroll
    for (int it = 0; it < 6; it++) {
        float4 v = *(const float4*)(base + it * 256 + lane * 4);
        re += v.x + v.z;
        im += v.y + v.w;
    }
#pragma unroll
    for (int o = 32; o; o >>= 1) {
        re += __shfl_xor(re, o);
        im += __shfl_xor(im, o);
    }
    if (lane == 0) msum[widx] = make_float2(re, im);
}

// ---------------- build spatial conv kernel k[d][da*14+db] ----------------
__global__ __launch_bounds__(256) void build_k(const float2* __restrict__ msum,
                                               float* __restrict__ kbuf) {
    int d = blockIdx.x;
    int tid = threadIdx.x;
    __shared__ float mre[112], mim[112], ct[14], st[14];
    if (tid < 112) {
        float2 v = msum[(size_t)tid * 768 + d];
        mre[tid] = v.x;
        mim[tid] = v.y;
    }
    if (tid >= 112 && tid < 126) {
        int j = tid - 112;
        float ang = 6.28318530717958647692f * (float)j / 14.f;
        ct[j] = cosf(ang);
        st[j] = sinf(ang);
    }
    __syncthreads();
    if (tid < 196) {
        int da = tid / 14, db = tid % 14;
        float acc = 0.f;
        for (int u = 0; u < 14; u++) {
            int idx = (u * da) % 14;
#pragma unroll
            for (int v = 0; v < 8; v++) {
                float w = (v == 0 || v == 7) ? 1.f : 2.f;
                acc += w * (mre[u * 8 + v] * ct[idx] - mim[u * 8 + v] * st[idx]);
                idx += db;
                if (idx >= 14) idx -= 14;
            }
        }
        kbuf[(size_t)d * 196 + tid] = acc * (1.f / 196.f);
    }
}

// ---------------- per-channel 14x14 circular conv ----------------
__device__ __forceinline__ void conv_proc(int a, int p, int lane, const float* kl,
                                          const float (&tq)[14], float (&ac)[14]) {
    int ra = a - p;
    if (ra < 0) ra += 14;
    const float* kr = &kl[lane * 197 + ra * 14];
    float kq[14];
#pragma unroll
    for (int i = 0; i < 14; i++) kq[i] = kr[i];
#pragma unroll
    for (int b = 0; b < 14; b++)
#pragma unroll
        for (int q = 0; q < 14; q++) ac[b] += tq[q] * kq[(b - q + 14) % 14];
}

__global__ __launch_bounds__(256) void conv_kernel(const float* __restrict__ x,
                                                   const float* __restrict__ kbuf,
                                                   float* __restrict__ t2) {
    __shared__ float tl[196 * 32];  // [s'][dlane]
    __shared__ float kl[32 * 197];  // [dlane][rel] pitch 197
    int n = blockIdx.x / 24;
    int d0 = (blockIdx.x % 24) * 32;
    int tid = threadIdx.x;
    for (int i = tid; i < 196 * 32; i += 256) {
        int s = i >> 5, dl = i & 31;
        tl[i] = x[((size_t)n * 197 + 1 + s) * 768 + d0 + dl];
    }
    for (int i = tid; i < 32 * 196; i += 256) {
        int dl = i / 196, j = i - dl * 196;
        kl[dl * 197 + j] = kbuf[(size_t)(d0 + dl) * 196 + j];
    }
    __syncthreads();
    int lane = tid & 31, sg = tid >> 5;
    bool two = (sg < 6);
    int a0 = two ? sg * 2 : 12 + (sg - 6);
    float acc0[14], acc1[14];
#pragma unroll
    for (int i = 0; i < 14; i++) {
        acc0[i] = 0.f;
        acc1[i] = 0.f;
    }
    for (int p = 0; p < 14; p++) {
        float tq[14];
#pragma unroll
        for (int q = 0; q < 14; q++) tq[q] = tl[(p * 14 + q) * 32 + lane];
        conv_proc(a0, p, lane, kl, tq, acc0);
        if (two) conv_proc(a0 + 1, p, lane, kl, tq, acc1);
    }
    __syncthreads();
#pragma unroll
    for (int b = 0; b < 14; b++) tl[(a0 * 14 + b) * 32 + lane] = acc0[b];
    if (two) {
#pragma unroll
        for (int b = 0; b < 14; b++) tl[((a0 + 1) * 14 + b) * 32 + lane] = acc1[b];
    }
    __syncthreads();
    for (int i = tid; i < 196 * 32; i += 256) {
        int s = i >> 5, dl = i & 31;
        t2[((size_t)n * 196 + s) * 768 + d0 + dl] = tl[i];
    }
}

// ---------------- attention (1 query per head, algebraically folded) ----------------
__device__ __forceinline__ float blk_sum(float v, float* red) {
    int lane = threadIdx.x & 63, wid = threadIdx.x >> 6;
#pragma unroll
    for (int o = 32; o; o >>= 1) v += __shfl_xor(v, o);
    if (lane == 0) red[wid] = v;
    __syncthreads();
    float r = red[0] + red[1] + red[2] + red[3];
    __syncthreads();
    return r;
}
__device__ __forceinline__ float blk_max(float v, float* red) {
    int lane = threadIdx.x & 63, wid = threadIdx.x >> 6;
#pragma unroll
    for (int o = 32; o; o >>= 1) v = fmaxf(v, __shfl_xor(v, o));
    if (lane == 0) red[wid] = v;
    __syncthreads();
    float r = fmaxf(fmaxf(red[0], red[1]), fmaxf(red[2], red[3]));
    __syncthreads();
    return r;
}

__global__ __launch_bounds__(256) void attn_kernel(
    const float* __restrict__ x, const float* __restrict__ t2, const float* __restrict__ Qw,
    const float* __restrict__ Qb, const float* __restrict__ Kw, const float* __restrict__ Kb,
    const float* __restrict__ Vw, const float* __restrict__ Vb, float* __restrict__ newcls) {
    int n = blockIdx.x / 12, h = blockIdx.x % 12;
    int tid = threadIdx.x;
    __shared__ float cls_s[64], Qp[64], gv[64], Aw[197], fv[64];
    __shared__ float red[8];
    const float* xn = x + (size_t)n * 197 * 768;
    if (tid < 64) cls_s[tid] = xn[h * 64 + tid];
    __syncthreads();
    if (tid < 64) {
        float s = 0.f;
        const float* qw = Qw + (size_t)tid * 768 + h * 64;
#pragma unroll 8
        for (int d = 0; d < 64; d++) s += cls_s[d] * qw[d];
        Qp[tid] = s + Qb[h];
    }
    __syncthreads();
    float sQ = blk_sum(tid < 64 ? Qp[tid] : 0.f, red);
    if (tid < 64) {
        float s = 0.f;
        for (int xq = 0; xq < 64; xq++) s += Qp[xq] * Kw[(size_t)xq * 768 + h * 64 + tid];
        gv[tid] = s;
    }
    __syncthreads();
    float apre = -3.0e38f;
    if (tid < 197) {
        const float* fr =
            (tid == 0) ? (xn + h * 64) : (t2 + ((size_t)n * 196 + tid - 1) * 768 + h * 64);
        float s = 0.f;
#pragma unroll 8
        for (int d = 0; d < 64; d++) s += fr[d] * gv[d];
        apre = (s + Kb[tid * 12 + h] * sQ) * 0.125f;
    }
    float mx = blk_max(apre, red);
    float p = (tid < 197) ? __expf(apre - mx) : 0.f;
    float denom = blk_sum(p, red);
    float sAV = blk_sum(tid < 197 ? p * Vb[tid * 12 + h] : 0.f, red) / denom;
    if (tid < 197) Aw[tid] = p / denom;
    __syncthreads();
    if (tid < 64) {
        float s = 0.f;
        for (int k = 0; k < 197; k++) {
            const float* fr = (k == 0) ? xn : (t2 + ((size_t)n * 196 + k - 1) * 768);
            s += Aw[k] * fr[h * 64 + tid];
        }
        fv[tid] = s;
    }
    __syncthreads();
    if (tid < 64) {
        float s = 0.f;
        for (int d = 0; d < 64; d++) s += fv[d] * Vw[(size_t)tid * 768 + h * 64 + d];
        newcls[(size_t)n * 768 + h * 64 + tid] = s + sAV;
    }
}

// ---------------- residual + layernorm; writes xo (fp32) and Y (bf16) ----------------
__global__ __launch_bounds__(256) void ln_kernel(const float* __restrict__ x,
                                                 const float* __restrict__ t2,
                                                 const float* __restrict__ newcls,
                                                 const float* __restrict__ lnw,
                                                 const float* __restrict__ lnb,
                                                 float* __restrict__ xo, u16* __restrict__ Y) {
    int row = blockIdx.x;
    int n = row / 197, g = row % 197;
    int tid = threadIdx.x;
    __shared__ float red[8], red2[8];
    const float* xr = x + (size_t)row * 768;
    const float* add = (g == 0) ? (newcls + (size_t)n * 768) : (t2 + ((size_t)n * 196 + g - 1) * 768);
    float v[3];
    float s = 0.f, s2 = 0.f;
#pragma unroll
    for (int j = 0; j < 3; j++) {
        int c = tid + j * 256;
        float t = xr[c] + add[c];
        v[j] = t;
        s += t;
        s2 += t * t;
    }
    int lane = tid & 63, wid = tid >> 6;
#pragma unroll
    for (int o = 32; o; o >>= 1) {
        s += __shfl_xor(s, o);
        s2 += __shfl_xor(s2, o);
    }
    if (lane == 0) {
        red[wid] = s;
        red2[wid] = s2;
    }
    __syncthreads();
    s = red[0] + red[1] + red[2] + red[3];
    s2 = red2[0] + red2[1] + red2[2] + red2[3];
    float mu = s * (1.f / 768.f);
    float var = s2 * (1.f / 768.f) - mu * mu;
    float rstd = 1.f / sqrtf(var + 1e-6f);
#pragma unroll
    for (int j = 0; j < 3; j++) {
        int c = tid + j * 256;
        float t = v[j];
        xo[(size_t)row * 768 + c] = t;
        float y = (t - mu) * rstd * lnw[c] + lnb[c];
        Y[(size_t)row * 768 + c] = f2bf(y);
    }
}

// ---------------- fp32 -> bf16 transpose (for B matrices) ----------------
__global__ __launch_bounds__(256) void transpose_to_bf16(const float* __restrict__ in,
                                                         u16* __restrict__ out, int R, int C) {
    __shared__ float tile[32][33];
    int c0 = blockIdx.x * 32, r0 = blockIdx.y * 32;
    int tx = threadIdx.x & 31, ty = threadIdx.x >> 5;
    for (int j = ty; j < 32; j += 8) tile[j][tx] = in[(size_t)(r0 + j) * C + c0 + tx];
    __syncthreads();
    for (int j = ty; j < 32; j += 8) out[(size_t)(c0 + j) * R + r0 + tx] = f2bf(tile[tx][j]);
}

// ------------- 128xBN bf16 MFMA GEMM with global_load_lds staging -------------
// C = A(MxK) * Bt(NxK)^T.  BK=32, 4 waves (2x2), wave tile 64 x BN/2.
// EPI 0: Hbuf (bf16) = gelu(acc+bias).  EPI 1: out (fp32) = acc+bias+resid, rows<MROWS.
template <int EPI, int BN>
__global__ __launch_bounds__(256) void gemm_glds(const u16* __restrict__ A,
                                                 const u16* __restrict__ Bt, int K,
                                                 const float* __restrict__ bias,
                                                 const float* __restrict__ resid,
                                                 void* __restrict__ outv, int Nt) {
    __shared__ __align__(16) u16 As[128 * 32];
    __shared__ __align__(16) u16 Bs[BN * 32];
    constexpr int NI = BN / 32;  // B-fragments / acc cols per wave
    int m0 = blockIdx.y * 128, n0 = blockIdx.x * BN;
    int tid = threadIdx.x;
    int lane = tid & 63, w = tid >> 6, wr = w >> 1, wc = w & 1;
    int lr = lane & 15, lkb = (lane >> 4) * 8;
    int lrow = lane >> 2, lcol = (lane & 3) * 8;  // lane's slot within a 16-row x 32-col chunk

    // staging: wave w owns A rows [w*32, w*32+32) as two 1KB chunks; B analogous
    const u16* Ag0 = A + (size_t)(m0 + w * 32 + lrow) * K + lcol;
    const u16* Ag1 = Ag0 + (size_t)16 * K;
    u16* Al0 = &As[(w * 32) * 32];
    u16* Al1 = &As[(w * 32 + 16) * 32];
    const u16* Bg0;
    const u16* Bg1 = nullptr;
    u16* Bl0;
    u16* Bl1 = nullptr;
    if constexpr (BN == 128) {
        Bg0 = Bt + (size_t)(n0 + w * 32 + lrow) * K + lcol;
        Bg1 = Bg0 + (size_t)16 * K;
        Bl0 = &Bs[(w * 32) * 32];
        Bl1 = &Bs[(w * 32 + 16) * 32];
    } else {  // BN == 64: one 1KB chunk per wave
        Bg0 = Bt + (size_t)(n0 + w * 16 + lrow) * K + lcol;
        Bl0 = &Bs[(w * 16) * 32];
    }

    f32x4 acc[4][NI];
#pragma unroll
    for (int i = 0; i < 4; i++)
#pragma unroll
        for (int j = 0; j < NI; j++) {
            f32x4 z = {0.f, 0.f, 0.f, 0.f};
            acc[i][j] = z;
        }

    for (int k0 = 0; k0 < K; k0 += 32) {
        gld16(Ag0 + k0, Al0);
        gld16(Ag1 + k0, Al1);
        gld16(Bg0 + k0, Bl0);
        if constexpr (BN == 128) gld16(Bg1 + k0, Bl1);
        __syncthreads();  // drains vmcnt (global_load_lds) before reads
        bf16x8 af[4], bfr[NI];
#pragma unroll
        for (int i = 0; i < 4; i++) af[i] = *(const bf16x8*)&As[(wr * 64 + i * 16 + lr) * 32 + lkb];
#pragma unroll
        for (int i = 0; i < NI; i++)
            bfr[i] = *(const bf16x8*)&Bs[(wc * (BN / 2) + i * 16 + lr) * 32 + lkb];
#pragma unroll
        for (int mi = 0; mi < 4; mi++)
#pragma unroll
            for (int ni = 0; ni < NI; ni++)
                acc[mi][ni] =
                    __builtin_amdgcn_mfma_f32_16x16x32_bf16(af[mi], bfr[ni], acc[mi][ni], 0, 0, 0);
        __syncthreads();  // protect LDS before next stage
    }

    int rbase = (lane >> 4) * 4;
#pragma unroll
    for (int mi = 0; mi < 4; mi++)
#pragma unroll
        for (int ni = 0; ni < NI; ni++) {
            int colg = n0 + wc * (BN / 2) + ni * 16 + lr;
#pragma unroll
            for (int r = 0; r < 4; r++) {
                int rowg = m0 + wr * 64 + mi * 16 + rbase + r;
                float a = acc[mi][ni][r];
                if (EPI == 0) {
                    float h = a + bias[colg];
                    h = 0.5f * h * (1.f + erff(h * 0.70710678118654752f));
                    ((u16*)outv)[(size_t)rowg * Nt + colg] = f2bf(h);
                } else {
                    if (rowg < MROWS) {
                        float h = a + bias[colg] + resid[(size_t)rowg * 768 + colg];
                        ((float*)outv)[(size_t)rowg * Nt + colg] = h;
                    }
                }
            }
        }
}

extern "C" void kernel_launch(void* const* d_in, const int* in_sizes, int n_in, void* d_out,
                              int out_size, void* d_ws, size_t ws_size, hipStream_t stream) {
    const float* x = (const float*)d_in[0];
    const float* mixer = (const float*)d_in[1];
    const float* Qw = (const float*)d_in[2];
    const float* Qb = (const float*)d_in[3];
    const float* Kw = (const float*)d_in[4];
    const float* Kb = (const float*)d_in[5];
    const float* Vw = (const float*)d_in[6];
    const float* Vb = (const float*)d_in[7];
    const float* lnw = (const float*)d_in[8];
    const float* lnb = (const float*)d_in[9];
    const float* w1 = (const float*)d_in[10];
    const float* b1 = (const float*)d_in[11];
    const float* w2 = (const float*)d_in[12];
    const float* b2 = (const float*)d_in[13];
    char* ws = (char*)d_ws;

    size_t off = 0;
    auto alloc = [&](size_t bytes) {
        size_t o = off;
        off += (bytes + 255) & ~(size_t)255;
        return o;
    };
    float2* msum = (float2*)(ws + alloc((size_t)14 * 8 * 768 * 8));
    float* kbuf = (float*)(ws + alloc((size_t)768 * 196 * 4));
    float* t2 = (float*)(ws + alloc((size_t)32 * 196 * 768 * 4));
    float* newcls = (float*)(ws + alloc((size_t)32 * 768 * 4));
    float* xo = (float*)(ws + alloc((size_t)32 * 197 * 768 * 4));
    u16* Ybuf = (u16*)(ws + alloc((size_t)MPAD * 768 * 2));
    u16* Hbuf = (u16*)(ws + alloc((size_t)MPAD * 3072 * 2));
    u16* w1t = (u16*)(ws + alloc((size_t)3072 * 768 * 2));
    u16* w2t = (u16*)(ws + alloc((size_t)768 * 3072 * 2));
    if (off > ws_size) return;

    transpose_to_bf16<<<dim3(3072 / 32, 768 / 32), 256, 0, stream>>>(w1, w1t, 768, 3072);
    transpose_to_bf16<<<dim3(768 / 32, 3072 / 32), 256, 0, stream>>>(w2, w2t, 3072, 768);
    reduce_mixer<<<21504, 256, 0, stream>>>(mixer, msum);
    build_k<<<768, 256, 0, stream>>>(msum, kbuf);
    conv_kernel<<<768, 256, 0, stream>>>(x, kbuf, t2);
    attn_kernel<<<384, 256, 0, stream>>>(x, t2, Qw, Qb, Kw, Kb, Vw, Vb, newcls);
    ln_kernel<<<6304, 256, 0, stream>>>(x, t2, newcls, lnw, lnb, xo, Ybuf);
    gemm_glds<0, 128><<<dim3(3072 / 128, 50), 256, 0, stream>>>(Ybuf, w1t, 768, b1, nullptr, Hbuf, 3072);
    gemm_glds<1, 64><<<dim3(768 / 64, 50), 256, 0, stream>>>(Hbuf, w2t, 3072, b2, xo, d_out, 768);
}

// Round 5
// 935.890 us; speedup vs baseline: 1.0259x; 1.0036x over previous
//
#include <hip/hip_runtime.h>
#include <hip/hip_bf16.h>

typedef unsigned short u16;
typedef short bf16x8 __attribute__((ext_vector_type(8)));
typedef float f32x4 __attribute__((ext_vector_type(4)));

#define N_ 32
#define G_ 197
#define C_ 768
#define HEADS_ 12
#define D_ 64
#define HH_ 14
#define FF_ 8
#define MLP_ 3072
#define MPAD 6400
#define MROWS 6304

__device__ __forceinline__ u16 f2bf(float f) {
    unsigned int u = __float_as_uint(f);
    u += 0x7FFF + ((u >> 16) & 1);
    return (u16)(u >> 16);
}

// async global->LDS 16B: lane l's 16B from g(lane-varying) lands at l(wave-uniform) + l*16
__device__ __forceinline__ void gld16(const void* g, void* l) {
#if __has_builtin(__builtin_amdgcn_global_load_lds)
    auto gp = reinterpret_cast<const __attribute__((address_space(1))) unsigned int*>(
        reinterpret_cast<uintptr_t>(g));
    auto lp = reinterpret_cast<__attribute__((address_space(3))) unsigned int*>(
        reinterpret_cast<uintptr_t>(l));
    __builtin_amdgcn_global_load_lds(gp, lp, 16, 0, 0);
#else
    int lane = threadIdx.x & 63;
    *(uint4*)((char*)l + lane * 16) = *(const uint4*)((const char*)g);
#endif
}

// ---------------- mixer reduce: msum[h,f,d] = sum_s mixer[h,f,d,s,:] ----------------
__global__ __launch_bounds__(256) void reduce_mixer(const float* __restrict__ mixer,
                                                    float2* __restrict__ msum) {
    int lane = threadIdx.x & 63;
    size_t widx = (size_t)blockIdx.x * 4 + (threadIdx.x >> 6);  // 0..86015 = (h*8+f)*768+d
    const float* base = mixer + widx * 1536;
    float re = 0.f, im = 0.f;
#pragma unroll
    for (int it = 0; it < 6; it++) {
        float4 v = *(const float4*)(base + it * 256 + lane * 4);
        re += v.x + v.z;
        im += v.y + v.w;
    }
#pragma unroll
    for (int o = 32; o; o >>= 1) {
        re += __shfl_xor(re, o);
        im += __shfl_xor(im, o);
    }
    if (lane == 0) msum[widx] = make_float2(re, im);
}

// ---------------- build spatial conv kernel k[d][da*14+db] ----------------
__global__ __launch_bounds__(256) void build_k(const float2* __restrict__ msum,
                                               float* __restrict__ kbuf) {
    int d = blockIdx.x;
    int tid = threadIdx.x;
    __shared__ float mre[112], mim[112], ct[14], st[14];
    if (tid < 112) {
        float2 v = msum[(size_t)tid * 768 + d];
        mre[tid] = v.x;
        mim[tid] = v.y;
    }
    if (tid >= 112 && tid < 126) {
        int j = tid - 112;
        float ang = 6.28318530717958647692f * (float)j / 14.f;
        ct[j] = cosf(ang);
        st[j] = sinf(ang);
    }
    __syncthreads();
    if (tid < 196) {
        int da = tid / 14, db = tid % 14;
        float acc = 0.f;
        for (int u = 0; u < 14; u++) {
            int idx = (u * da) % 14;
#pragma unroll
            for (int v = 0; v < 8; v++) {
                float w = (v == 0 || v == 7) ? 1.f : 2.f;
                acc += w * (mre[u * 8 + v] * ct[idx] - mim[u * 8 + v] * st[idx]);
                idx += db;
                if (idx >= 14) idx -= 14;
            }
        }
        kbuf[(size_t)d * 196 + tid] = acc * (1.f / 196.f);
    }
}

// ---------------- per-channel 14x14 circular conv ----------------
__device__ __forceinline__ void conv_proc(int a, int p, int lane, const float* kl,
                                          const float (&tq)[14], float (&ac)[14]) {
    int ra = a - p;
    if (ra < 0) ra += 14;
    const float* kr = &kl[lane * 197 + ra * 14];
    float kq[14];
#pragma unroll
    for (int i = 0; i < 14; i++) kq[i] = kr[i];
#pragma unroll
    for (int b = 0; b < 14; b++)
#pragma unroll
        for (int q = 0; q < 14; q++) ac[b] += tq[q] * kq[(b - q + 14) % 14];
}

__global__ __launch_bounds__(256) void conv_kernel(const float* __restrict__ x,
                                                   const float* __restrict__ kbuf,
                                                   float* __restrict__ t2) {
    __shared__ float tl[196 * 32];  // [s'][dlane]
    __shared__ float kl[32 * 197];  // [dlane][rel] pitch 197
    int n = blockIdx.x / 24;
    int d0 = (blockIdx.x % 24) * 32;
    int tid = threadIdx.x;
    for (int i = tid; i < 196 * 32; i += 256) {
        int s = i >> 5, dl = i & 31;
        tl[i] = x[((size_t)n * 197 + 1 + s) * 768 + d0 + dl];
    }
    for (int i = tid; i < 32 * 196; i += 256) {
        int dl = i / 196, j = i - dl * 196;
        kl[dl * 197 + j] = kbuf[(size_t)(d0 + dl) * 196 + j];
    }
    __syncthreads();
    int lane = tid & 31, sg = tid >> 5;
    bool two = (sg < 6);
    int a0 = two ? sg * 2 : 12 + (sg - 6);
    float acc0[14], acc1[14];
#pragma unroll
    for (int i = 0; i < 14; i++) {
        acc0[i] = 0.f;
        acc1[i] = 0.f;
    }
    for (int p = 0; p < 14; p++) {
        float tq[14];
#pragma unroll
        for (int q = 0; q < 14; q++) tq[q] = tl[(p * 14 + q) * 32 + lane];
        conv_proc(a0, p, lane, kl, tq, acc0);
        if (two) conv_proc(a0 + 1, p, lane, kl, tq, acc1);
    }
    __syncthreads();
#pragma unroll
    for (int b = 0; b < 14; b++) tl[(a0 * 14 + b) * 32 + lane] = acc0[b];
    if (two) {
#pragma unroll
        for (int b = 0; b < 14; b++) tl[((a0 + 1) * 14 + b) * 32 + lane] = acc1[b];
    }
    __syncthreads();
    for (int i = tid; i < 196 * 32; i += 256) {
        int s = i >> 5, dl = i & 31;
        t2[((size_t)n * 196 + s) * 768 + d0 + dl] = tl[i];
    }
}

// ---------------- attention (1 query per head, algebraically folded) ----------------
__device__ __forceinline__ float blk_sum(float v, float* red) {
    int lane = threadIdx.x & 63, wid = threadIdx.x >> 6;
#pragma unroll
    for (int o = 32; o; o >>= 1) v += __shfl_xor(v, o);
    if (lane == 0) red[wid] = v;
    __syncthreads();
    float r = red[0] + red[1] + red[2] + red[3];
    __syncthreads();
    return r;
}
__device__ __forceinline__ float blk_max(float v, float* red) {
    int lane = threadIdx.x & 63, wid = threadIdx.x >> 6;
#pragma unroll
    for (int o = 32; o; o >>= 1) v = fmaxf(v, __shfl_xor(v, o));
    if (lane == 0) red[wid] = v;
    __syncthreads();
    float r = fmaxf(fmaxf(red[0], red[1]), fmaxf(red[2], red[3]));
    __syncthreads();
    return r;
}

__global__ __launch_bounds__(256) void attn_kernel(
    const float* __restrict__ x, const float* __restrict__ t2, const float* __restrict__ Qw,
    const float* __restrict__ Qb, const float* __restrict__ Kw, const float* __restrict__ Kb,
    const float* __restrict__ Vw, const float* __restrict__ Vb, float* __restrict__ newcls) {
    int n = blockIdx.x / 12, h = blockIdx.x % 12;
    int tid = threadIdx.x;
    __shared__ float cls_s[64], Qp[64], gv[64], Aw[197], fv[64];
    __shared__ float red[8];
    const float* xn = x + (size_t)n * 197 * 768;
    if (tid < 64) cls_s[tid] = xn[h * 64 + tid];
    __syncthreads();
    if (tid < 64) {
        float s = 0.f;
        const float* qw = Qw + (size_t)tid * 768 + h * 64;
#pragma unroll 8
        for (int d = 0; d < 64; d++) s += cls_s[d] * qw[d];
        Qp[tid] = s + Qb[h];
    }
    __syncthreads();
    float sQ = blk_sum(tid < 64 ? Qp[tid] : 0.f, red);
    if (tid < 64) {
        float s = 0.f;
        for (int xq = 0; xq < 64; xq++) s += Qp[xq] * Kw[(size_t)xq * 768 + h * 64 + tid];
        gv[tid] = s;
    }
    __syncthreads();
    float apre = -3.0e38f;
    if (tid < 197) {
        const float* fr =
            (tid == 0) ? (xn + h * 64) : (t2 + ((size_t)n * 196 + tid - 1) * 768 + h * 64);
        float s = 0.f;
#pragma unroll 8
        for (int d = 0; d < 64; d++) s += fr[d] * gv[d];
        apre = (s + Kb[tid * 12 + h] * sQ) * 0.125f;
    }
    float mx = blk_max(apre, red);
    float p = (tid < 197) ? __expf(apre - mx) : 0.f;
    float denom = blk_sum(p, red);
    float sAV = blk_sum(tid < 197 ? p * Vb[tid * 12 + h] : 0.f, red) / denom;
    if (tid < 197) Aw[tid] = p / denom;
    __syncthreads();
    if (tid < 64) {
        float s = 0.f;
        for (int k = 0; k < 197; k++) {
            const float* fr = (k == 0) ? xn : (t2 + ((size_t)n * 196 + k - 1) * 768);
            s += Aw[k] * fr[h * 64 + tid];
        }
        fv[tid] = s;
    }
    __syncthreads();
    if (tid < 64) {
        float s = 0.f;
        for (int d = 0; d < 64; d++) s += fv[d] * Vw[(size_t)tid * 768 + h * 64 + d];
        newcls[(size_t)n * 768 + h * 64 + tid] = s + sAV;
    }
}

// ---------------- residual + layernorm; writes xo (fp32) and Y (bf16) ----------------
__global__ __launch_bounds__(256) void ln_kernel(const float* __restrict__ x,
                                                 const float* __restrict__ t2,
                                                 const float* __restrict__ newcls,
                                                 const float* __restrict__ lnw,
                                                 const float* __restrict__ lnb,
                                                 float* __restrict__ xo, u16* __restrict__ Y) {
    int row = blockIdx.x;
    int n = row / 197, g = row % 197;
    int tid = threadIdx.x;
    __shared__ float red[8], red2[8];
    const float* xr = x + (size_t)row * 768;
    const float* add = (g == 0) ? (newcls + (size_t)n * 768) : (t2 + ((size_t)n * 196 + g - 1) * 768);
    float v[3];
    float s = 0.f, s2 = 0.f;
#pragma unroll
    for (int j = 0; j < 3; j++) {
        int c = tid + j * 256;
        float t = xr[c] + add[c];
        v[j] = t;
        s += t;
        s2 += t * t;
    }
    int lane = tid & 63, wid = tid >> 6;
#pragma unroll
    for (int o = 32; o; o >>= 1) {
        s += __shfl_xor(s, o);
        s2 += __shfl_xor(s2, o);
    }
    if (lane == 0) {
        red[wid] = s;
        red2[wid] = s2;
    }
    __syncthreads();
    s = red[0] + red[1] + red[2] + red[3];
    s2 = red2[0] + red2[1] + red2[2] + red2[3];
    float mu = s * (1.f / 768.f);
    float var = s2 * (1.f / 768.f) - mu * mu;
    float rstd = 1.f / sqrtf(var + 1e-6f);
#pragma unroll
    for (int j = 0; j < 3; j++) {
        int c = tid + j * 256;
        float t = v[j];
        xo[(size_t)row * 768 + c] = t;
        float y = (t - mu) * rstd * lnw[c] + lnb[c];
        Y[(size_t)row * 768 + c] = f2bf(y);
    }
}

// ------ fp32 -> bf16 transpose of BOTH weight matrices in one dispatch ------
// blocks 0..2303: w1 (768x3072 -> 3072x768); blocks 2304..4607: w2 (3072x768 -> 768x3072)
__global__ __launch_bounds__(256) void transpose_both(const float* __restrict__ w1,
                                                      const float* __restrict__ w2,
                                                      u16* __restrict__ w1t,
                                                      u16* __restrict__ w2t) {
    __shared__ float tile[32][33];
    int bid = blockIdx.x;
    const float* in;
    u16* out;
    int R, C, c0, r0;
    if (bid < 2304) {
        in = w1; out = w1t; R = 768; C = 3072;
        c0 = (bid % 96) * 32; r0 = (bid / 96) * 32;
    } else {
        int b2 = bid - 2304;
        in = w2; out = w2t; R = 3072; C = 768;
        c0 = (b2 % 24) * 32; r0 = (b2 / 24) * 32;
    }
    int tx = threadIdx.x & 31, ty = threadIdx.x >> 5;
    for (int j = ty; j < 32; j += 8) tile[j][tx] = in[(size_t)(r0 + j) * C + c0 + tx];
    __syncthreads();
    for (int j = ty; j < 32; j += 8) out[(size_t)(c0 + j) * R + r0 + tx] = f2bf(tile[tx][j]);
}

// ------------- 128x128 bf16 MFMA GEMM with global_load_lds staging -------------
// C = A(MxK) * Bt(NxK)^T.  BK=32, 4 waves (2x2), wave tile 64x64, acc 4x4.
// K-range per block: [z*K/gridDim.z , +K/gridDim.z) with z = blockIdx.z.
// EPI 0: Hbuf (bf16) = gelu(acc+bias).
// EPI 2: partial (fp32) = acc, written to outv + z*MPAD*Nt (split-K).
template <int EPI>
__global__ __launch_bounds__(256) void gemm_glds(const u16* __restrict__ A,
                                                 const u16* __restrict__ Bt, int K,
                                                 const float* __restrict__ bias,
                                                 void* __restrict__ outv, int Nt) {
    __shared__ __align__(16) u16 As[128 * 32];
    __shared__ __align__(16) u16 Bs[128 * 32];
    int m0 = blockIdx.y * 128, n0 = blockIdx.x * 128;
    int tid = threadIdx.x;
    int lane = tid & 63, w = tid >> 6, wr = w >> 1, wc = w & 1;
    int lr = lane & 15, lkb = (lane >> 4) * 8;
    int lrow = lane >> 2, lcol = (lane & 3) * 8;  // lane's slot within a 16-row x 32-col chunk
    int kspan = K / gridDim.z;
    int kbeg = blockIdx.z * kspan, kend = kbeg + kspan;

    // staging: wave w owns A rows [w*32, w*32+32) as two 1KB chunks; B analogous
    const u16* Ag0 = A + (size_t)(m0 + w * 32 + lrow) * K + lcol;
    const u16* Ag1 = Ag0 + (size_t)16 * K;
    u16* Al0 = &As[(w * 32) * 32];
    u16* Al1 = &As[(w * 32 + 16) * 32];
    const u16* Bg0 = Bt + (size_t)(n0 + w * 32 + lrow) * K + lcol;
    const u16* Bg1 = Bg0 + (size_t)16 * K;
    u16* Bl0 = &Bs[(w * 32) * 32];
    u16* Bl1 = &Bs[(w * 32 + 16) * 32];

    f32x4 acc[4][4];
#pragma unroll
    for (int i = 0; i < 4; i++)
#pragma unroll
        for (int j = 0; j < 4; j++) {
            f32x4 z = {0.f, 0.f, 0.f, 0.f};
            acc[i][j] = z;
        }

    for (int k0 = kbeg; k0 < kend; k0 += 32) {
        gld16(Ag0 + k0, Al0);
        gld16(Ag1 + k0, Al1);
        gld16(Bg0 + k0, Bl0);
        gld16(Bg1 + k0, Bl1);
        __syncthreads();  // drains vmcnt (global_load_lds) before reads
        bf16x8 af[4], bfr[4];
#pragma unroll
        for (int i = 0; i < 4; i++) {
            af[i] = *(const bf16x8*)&As[(wr * 64 + i * 16 + lr) * 32 + lkb];
            bfr[i] = *(const bf16x8*)&Bs[(wc * 64 + i * 16 + lr) * 32 + lkb];
        }
#pragma unroll
        for (int mi = 0; mi < 4; mi++)
#pragma unroll
            for (int ni = 0; ni < 4; ni++)
                acc[mi][ni] =
                    __builtin_amdgcn_mfma_f32_16x16x32_bf16(af[mi], bfr[ni], acc[mi][ni], 0, 0, 0);
        __syncthreads();  // protect LDS before next stage
    }

    int rbase = (lane >> 4) * 4;
    float* pout = (float*)outv + (size_t)blockIdx.z * MPAD * Nt;
#pragma unroll
    for (int mi = 0; mi < 4; mi++)
#pragma unroll
        for (int ni = 0; ni < 4; ni++) {
            int colg = n0 + wc * 64 + ni * 16 + lr;
#pragma unroll
            for (int r = 0; r < 4; r++) {
                int rowg = m0 + wr * 64 + mi * 16 + rbase + r;
                float a = acc[mi][ni][r];
                if (EPI == 0) {
                    float h = a + bias[colg];
                    h = 0.5f * h * (1.f + erff(h * 0.70710678118654752f));
                    ((u16*)outv)[(size_t)rowg * Nt + colg] = f2bf(h);
                } else {
                    pout[(size_t)rowg * Nt + colg] = a;
                }
            }
        }
}

// ---- combine split-K partials + bias + residual -> fp32 output (rows < MROWS) ----
__global__ __launch_bounds__(256) void combine_out(const float* __restrict__ part,
                                                   const float* __restrict__ b2,
                                                   const float* __restrict__ xo,
                                                   float* __restrict__ out) {
    int idx = blockIdx.x * 256 + threadIdx.x;  // float4 index
    if (idx >= MROWS * 768 / 4) return;
    int c = (idx * 4) % 768;
    const float4 p0 = *(const float4*)&part[(size_t)idx * 4];
    const float4 p1 = *(const float4*)&part[(size_t)MPAD * 768 + idx * 4];
    const float4 rz = *(const float4*)&xo[(size_t)idx * 4];
    const float4 bb = *(const float4*)&b2[c];
    float4 o;
    o.x = p0.x + p1.x + rz.x + bb.x;
    o.y = p0.y + p1.y + rz.y + bb.y;
    o.z = p0.z + p1.z + rz.z + bb.z;
    o.w = p0.w + p1.w + rz.w + bb.w;
    *(float4*)&out[(size_t)idx * 4] = o;
}

extern "C" void kernel_launch(void* const* d_in, const int* in_sizes, int n_in, void* d_out,
                              int out_size, void* d_ws, size_t ws_size, hipStream_t stream) {
    const float* x = (const float*)d_in[0];
    const float* mixer = (const float*)d_in[1];
    const float* Qw = (const float*)d_in[2];
    const float* Qb = (const float*)d_in[3];
    const float* Kw = (const float*)d_in[4];
    const float* Kb = (const float*)d_in[5];
    const float* Vw = (const float*)d_in[6];
    const float* Vb = (const float*)d_in[7];
    const float* lnw = (const float*)d_in[8];
    const float* lnb = (const float*)d_in[9];
    const float* w1 = (const float*)d_in[10];
    const float* b1 = (const float*)d_in[11];
    const float* w2 = (const float*)d_in[12];
    const float* b2 = (const float*)d_in[13];
    char* ws = (char*)d_ws;

    size_t off = 0;
    auto alloc = [&](size_t bytes) {
        size_t o = off;
        off += (bytes + 255) & ~(size_t)255;
        return o;
    };
    float2* msum = (float2*)(ws + alloc((size_t)14 * 8 * 768 * 8));
    float* kbuf = (float*)(ws + alloc((size_t)768 * 196 * 4));
    float* t2 = (float*)(ws + alloc((size_t)32 * 196 * 768 * 4));
    float* newcls = (float*)(ws + alloc((size_t)32 * 768 * 4));
    float* xo = (float*)(ws + alloc((size_t)32 * 197 * 768 * 4));
    u16* Ybuf = (u16*)(ws + alloc((size_t)MPAD * 768 * 2));
    u16* Hbuf = (u16*)(ws + alloc((size_t)MPAD * 3072 * 2));
    u16* w1t = (u16*)(ws + alloc((size_t)3072 * 768 * 2));
    u16* w2t = (u16*)(ws + alloc((size_t)768 * 3072 * 2));
    float* part = (float*)(ws + alloc((size_t)2 * MPAD * 768 * 4));
    if (off > ws_size) return;

    transpose_both<<<4608, 256, 0, stream>>>(w1, w2, w1t, w2t);
    reduce_mixer<<<21504, 256, 0, stream>>>(mixer, msum);
    build_k<<<768, 256, 0, stream>>>(msum, kbuf);
    conv_kernel<<<768, 256, 0, stream>>>(x, kbuf, t2);
    attn_kernel<<<384, 256, 0, stream>>>(x, t2, Qw, Qb, Kw, Kb, Vw, Vb, newcls);
    ln_kernel<<<6304, 256, 0, stream>>>(x, t2, newcls, lnw, lnb, xo, Ybuf);
    gemm_glds<0><<<dim3(3072 / 128, 50, 1), 256, 0, stream>>>(Ybuf, w1t, 768, b1, Hbuf, 3072);
    gemm_glds<2><<<dim3(768 / 128, 50, 2), 256, 0, stream>>>(Hbuf, w2t, 3072, nullptr, part, 768);
    combine_out<<<(MROWS * 768 / 4 + 255) / 256, 256, 0, stream>>>(part, b2, xo, (float*)d_out);
}